// Round 5
// baseline (321.042 us; speedup 1.0000x reference)
//
#include <hip/hip_runtime.h>
#include <stdint.h>

// LSTM fused: B=8192, T=128, I=32, H=64, OUT=8. fp32 internal state, bf16 MFMA.
// R13 = R11's PASSING per-batch code with ONE structural change: 2-tile ILP.
// B_TILE 16 -> 32, grid 512 -> 256 (1 block/CU), 4 waves, each wave runs TWO
// independent 16-batch chains (tile A = batches 0..15, tile B = 16..31),
// interleaved A/B per step. Zero per-batch overhead added (unlike R12's
// garbage rows): same MFMA/trans/VALU count per batch as R11; barrier
// amortized over 2x payload; no inter-block SIMD contention.
// T_CHUNK 32 -> 16 so LDS = hbuf 18.4K + xbuf 40K = 59.4K < 64K; epilogue
// hfin aliases dead hbuf storage (separated by __syncthreads fences).
// __launch_bounds__(256,1): 1 wave/SIMD by design, VGPR headroom for 2x state.
// R12 post-mortem: 4 chains/SIMD via 8-batch blocks = issue-saturated
// (VALU 55 + MFMA 29 = 84%), per-batch cost +13% -> regressed. Garbage-row
// TLP is a dead end. R11 ledger: x-MFMA pipeline works ONLY as {loads hoisted
// to step top, accx MFMAs sunk after gates}; R10: bank conflicts off-path,
// HPAD=144 known-good. R9: do not widen barriers to 8 waves.
// NaN ledger: R1/R5/R7 (vector weight loads, plain body) and R6 (K=16 f16)
// all NaN'd; R2/R3/R8/R11 (scalar loads + sniff dispatcher) passed. Do not
// reintroduce those factors without an isolated A/B.

#define T_STEPS 128
#define ISZ 32
#define HSZ 64
#define B_TOT 8192
#define B_TILE 32
#define T_CHUNK 16
#define HPAD 144

typedef short bf16x8 __attribute__((ext_vector_type(8)));
typedef float f32x4 __attribute__((ext_vector_type(4)));

#define LOG2E 1.44269504088896340736f

__device__ __forceinline__ float bf2f(unsigned short s) {
    union { unsigned int u; float f; } v; v.u = ((unsigned int)s) << 16; return v.f;
}
__device__ __forceinline__ unsigned short f2bf(float f) {
    union { float f; unsigned int u; } v; v.f = f;
    unsigned int u = v.u;
    return (unsigned short)((u + 0x7fffu + ((u >> 16) & 1u)) >> 16);  // RNE
}
// sigmoid = rcp(1 + exp2(-x*log2e)); x->-inf: exp2->inf, rcp->0; x->+inf: 1. Safe.
__device__ __forceinline__ float sigf(float x) {
    return __builtin_amdgcn_rcpf(1.0f + __builtin_amdgcn_exp2f(-LOG2E * x));
}
// tanh = 1 - 2*rcp(1 + exp2(2x*log2e)); +inf -> 1; -inf -> -1. Safe.
__device__ __forceinline__ float tanh_fast(float x) {
    return 1.0f - 2.0f * __builtin_amdgcn_rcpf(1.0f + __builtin_amdgcn_exp2f((2.0f * LOG2E) * x));
}

template <bool F32>
__device__ __forceinline__ float ldin(const void* p, size_t i) {
    if (F32) return ((const float*)p)[i];
    return bf2f(((const unsigned short*)p)[i]);
}

template <bool F32>
__device__ __forceinline__ void run_body(
    const void* xv, const void* Wihv, const void* Whhv, const void* bihv,
    const void* bhhv, const void* Wfcv, const void* bfcv, void* outv,
    unsigned short (&hbuf)[2][B_TILE][HPAD],
    unsigned short (&xbuf)[T_CHUNK][B_TILE][40])
{
    const int tid  = threadIdx.x;
    const int wid  = tid >> 6;
    const int lane = tid & 63;
    const int q    = lane >> 4;   // A/B frag k-quad; C/D row-quad
    const int tn   = lane & 15;   // A: batch row m; B/C: unit col n
    const int u    = wid * 16 + tn;
    const int b0   = blockIdx.x * B_TILE;

    // B-operand weight frags, loaded once (scalar loads — see NaN ledger).
    bf16x8 wf[4][3];
    f32x4 biasC[4];   // bias broadcast into a C-operand vector: no acc-init movs
    #pragma unroll
    for (int g = 0; g < 4; ++g) {
        const int row = g * HSZ + u;
        #pragma unroll
        for (int j = 0; j < 8; ++j) {
            wf[g][0][j] = (short)f2bf(ldin<F32>(Whhv, row * HSZ + q * 8 + j));
            wf[g][1][j] = (short)f2bf(ldin<F32>(Whhv, row * HSZ + 32 + q * 8 + j));
            wf[g][2][j] = (short)f2bf(ldin<F32>(Wihv, row * ISZ + q * 8 + j));
        }
        const float b = ldin<F32>(bihv, row) + ldin<F32>(bhhv, row);
        #pragma unroll
        for (int e = 0; e < 4; ++e) biasC[g][e] = b;
    }

    // h(0) = 0
    for (int i = tid; i < 2 * B_TILE * HPAD; i += 256) ((unsigned short*)hbuf)[i] = 0;

    float cstA[4] = {0.f, 0.f, 0.f, 0.f};
    float cstB[4] = {0.f, 0.f, 0.f, 0.f};
    float hlA[4]  = {0.f, 0.f, 0.f, 0.f};
    float hlB[4]  = {0.f, 0.f, 0.f, 0.f};
    f32x4 accxA[4], accxB[4];

    for (int tc = 0; tc < T_STEPS / T_CHUNK; ++tc) {
        // stage x[b0..+32)[tc*16..+16)[0..32) -> xbuf[t][m][k]; prev chunk's
        // reads finished at the last step's barrier, so no barrier needed here.
        if (F32) {
            const float* xf = (const float*)xv;
            for (int idx = tid; idx < B_TILE * T_CHUNK * 4; idx += 256) {
                const int m  = idx >> 6;
                const int rm = idx & 63;
                const int tl = rm >> 2;
                const int ch = rm & 3;
                const size_t base = ((size_t)(b0 + m) * T_STEPS + (tc * T_CHUNK + tl)) * ISZ + ch * 8;
                const f32x4 v0 = *(const f32x4*)(xf + base);
                const f32x4 v1 = *(const f32x4*)(xf + base + 4);
                bf16x8 w;
                #pragma unroll
                for (int j = 0; j < 4; ++j) {
                    w[j]     = (short)f2bf(v0[j]);
                    w[4 + j] = (short)f2bf(v1[j]);
                }
                *(bf16x8*)&xbuf[tl][m][ch * 8] = w;
            }
        } else {
            const unsigned short* xu = (const unsigned short*)xv;
            for (int idx = tid; idx < B_TILE * T_CHUNK * 4; idx += 256) {
                const int m  = idx >> 6;
                const int rm = idx & 63;
                const int tl = rm >> 2;
                const int ch = rm & 3;
                const uint4 v = *(const uint4*)(xu + ((size_t)(b0 + m) * T_STEPS + (tc * T_CHUNK + tl)) * ISZ + ch * 8);
                *(uint4*)&xbuf[tl][m][ch * 8] = v;
            }
        }
        __syncthreads();

        // chunk prologue: x-contribution of step tl=0, both tiles (bias as C).
        {
            const bf16x8 axA = *(const bf16x8*)&xbuf[0][tn][q * 8];
            const bf16x8 axB = *(const bf16x8*)&xbuf[0][16 + tn][q * 8];
            #pragma unroll
            for (int g = 0; g < 4; ++g)
                accxA[g] = __builtin_amdgcn_mfma_f32_16x16x32_bf16(axA, wf[g][2], biasC[g], 0, 0, 0);
            #pragma unroll
            for (int g = 0; g < 4; ++g)
                accxB[g] = __builtin_amdgcn_mfma_f32_16x16x32_bf16(axB, wf[g][2], biasC[g], 0, 0, 0);
        }

        for (int tl = 0; tl < T_CHUNK; ++tl) {
            const int t  = tc * T_CHUNK + tl;
            const int rb = t & 1, wb = rb ^ 1;
            const int nt = (tl + 1) & (T_CHUNK - 1);
            // issue ALL step loads together: h A-frags (both tiles) + next
            // step's x frags. x waits deferred to last use (accx MFMAs).
            const bf16x8 aA0  = *(const bf16x8*)&hbuf[rb][tn][q * 8];
            const bf16x8 aA1  = *(const bf16x8*)&hbuf[rb][tn][32 + q * 8];
            const bf16x8 aB0  = *(const bf16x8*)&hbuf[rb][16 + tn][q * 8];
            const bf16x8 aB1  = *(const bf16x8*)&hbuf[rb][16 + tn][32 + q * 8];
            const bf16x8 axA2 = *(const bf16x8*)&xbuf[nt][tn][q * 8];
            const bf16x8 axB2 = *(const bf16x8*)&xbuf[nt][16 + tn][q * 8];

            f32x4 accA[4], accB[4];
            // interleave tile A / tile B MFMA issue: B's issue covers A's latency
            #pragma unroll
            for (int g = 0; g < 4; ++g)
                accA[g] = __builtin_amdgcn_mfma_f32_16x16x32_bf16(aA0, wf[g][0], accxA[g], 0, 0, 0);
            #pragma unroll
            for (int g = 0; g < 4; ++g)
                accB[g] = __builtin_amdgcn_mfma_f32_16x16x32_bf16(aB0, wf[g][0], accxB[g], 0, 0, 0);
            #pragma unroll
            for (int g = 0; g < 4; ++g)
                accA[g] = __builtin_amdgcn_mfma_f32_16x16x32_bf16(aA1, wf[g][1], accA[g], 0, 0, 0);
            #pragma unroll
            for (int g = 0; g < 4; ++g)
                accB[g] = __builtin_amdgcn_mfma_f32_16x16x32_bf16(aB1, wf[g][1], accB[g], 0, 0, 0);

            // gate trans phase, tile A then tile B (independent chains; the
            // compiler interleaves them — 2x ILP across the trans pipe).
            #pragma unroll
            for (int r = 0; r < 4; ++r) {
                const float gi = sigf(accA[0][r]);
                const float gf = sigf(accA[1][r]);
                const float gg = tanh_fast(accA[2][r]);
                const float go = sigf(accA[3][r]);
                cstA[r] = gf * cstA[r] + gi * gg;
                const float hv = go * tanh_fast(cstA[r]);
                hlA[r] = hv;
                hbuf[wb][q * 4 + r][u] = f2bf(hv);
            }
            #pragma unroll
            for (int r = 0; r < 4; ++r) {
                const float gi = sigf(accB[0][r]);
                const float gf = sigf(accB[1][r]);
                const float gg = tanh_fast(accB[2][r]);
                const float go = sigf(accB[3][r]);
                cstB[r] = gf * cstB[r] + gi * gg;
                const float hv = go * tanh_fast(cstB[r]);
                hlB[r] = hv;
                hbuf[wb][16 + q * 4 + r][u] = f2bf(hv);
            }

            // next step's x-contribution LAST: fills the write/barrier window.
            // nt wraps to stale xbuf[0] on the last step; that accx is
            // discarded (next chunk's prologue recomputes), and the read
            // precedes the staging barrier -> no race.
            #pragma unroll
            for (int g = 0; g < 4; ++g)
                accxA[g] = __builtin_amdgcn_mfma_f32_16x16x32_bf16(axA2, wf[g][2], biasC[g], 0, 0, 0);
            #pragma unroll
            for (int g = 0; g < 4; ++g)
                accxB[g] = __builtin_amdgcn_mfma_f32_16x16x32_bf16(axB2, wf[g][2], biasC[g], 0, 0, 0);

            __syncthreads();
        }
    }

    // epilogue: out[b][j] = h_T(fp32) . Wfc[j,:] + bfc[j]
    // hfin aliases dead hbuf storage (needs 8.7KB <= 18.4KB). The preceding
    // __syncthreads (end of last step) fences all prior hbuf accesses.
    float (*hfin)[HSZ + 4] = reinterpret_cast<float (*)[HSZ + 4]>(&hbuf[0][0][0]);
    #pragma unroll
    for (int r = 0; r < 4; ++r) {
        hfin[q * 4 + r][u]      = hlA[r];
        hfin[16 + q * 4 + r][u] = hlB[r];
    }
    __syncthreads();
    {
        const int m = tid >> 3, j = tid & 7;   // 256 threads = 32 batches x 8 outs
        float s = ldin<F32>(bfcv, j);
        #pragma unroll
        for (int k = 0; k < HSZ; ++k) s += hfin[m][k] * ldin<F32>(Wfcv, j * HSZ + k);
        const size_t o = (size_t)(b0 + m) * 8 + j;
        if (F32) ((float*)outv)[o] = s;
        else     ((unsigned short*)outv)[o] = f2bf(s);
    }
}

__global__ __launch_bounds__(256, 1) void lstm_fused(
    const void* __restrict__ x, const void* __restrict__ Wih,
    const void* __restrict__ Whh, const void* __restrict__ bih,
    const void* __restrict__ bhh, const void* __restrict__ Wfc,
    const void* __restrict__ bfc, void* __restrict__ out)
{
    __shared__ __align__(16) unsigned short hbuf[2][B_TILE][HPAD];
    __shared__ __align__(16) unsigned short xbuf[T_CHUNK][B_TILE][40];

    // dtype sniff (guard): fp32 data read as uint16 halves has mantissa-garbage
    // halves decoding to huge-exponent bf16s; real bf16 data never exceeds 2^17.
    const unsigned short* xu = (const unsigned short*)x;
    const int lane = threadIdx.x & 63;
    const unsigned short s0 = xu[lane * 2];
    const unsigned short s1 = xu[lane * 2 + 1];
    const int big = (((s0 >> 7) & 0xFF) >= 0x90) || (((s1 >> 7) & 0xFF) >= 0x90);
    const bool isf32 = __any(big) != 0;

    if (isf32) run_body<true >(x, Wih, Whh, bih, bhh, Wfc, bfc, out, hbuf, xbuf);
    else       run_body<false>(x, Wih, Whh, bih, bhh, Wfc, bfc, out, hbuf, xbuf);
}

extern "C" void kernel_launch(void* const* d_in, const int* in_sizes, int n_in,
                              void* d_out, int out_size, void* d_ws, size_t ws_size,
                              hipStream_t stream) {
    lstm_fused<<<dim3(B_TOT / B_TILE), dim3(256), 0, stream>>>(
        d_in[0], d_in[1], d_in[2], d_in[3], d_in[4], d_in[5], d_in[6], d_out);
}

// Round 6
// 268.340 us; speedup vs baseline: 1.1964x; 1.1964x over previous
//
#include <hip/hip_runtime.h>
#include <stdint.h>

// LSTM fused: B=8192, T=128, I=32, H=64, OUT=8. fp32 internal state, bf16 MFMA.
// R14 = R11 (best, 135.2us) + two critical-path issue cuts, structure frozen:
//   (1) exponent scale folded into weights at load: i/f/o rows of W (and
//       biases) pre-scaled by -LOG2E, g rows by +2*LOG2E (fp32 mul BEFORE the
//       single bf16 rounding -> same error profile). Gates become
//       rcp(1+exp2(acc)) directly: removes 4 v_mul per unit-update from the
//       HEAD of each trans chain (MFMA result feeds exp2 immediately).
//   (2) s_setprio(1) around the h-MFMA cluster (co-resident waves are from
//       different blocks at different phases -> the attn-positive case).
// Structure ledger (do not revisit): 2 waves/SIMD is the empirical optimum —
// R12 (4 chains, 8-batch blocks) 154us, R13 (1 chain, 32-batch 2-tile ILP)
// 185us, R9 (8-wave blocks) 184us. Stall ~1400cyc/step is structural
// (barrier lockstep + LDS turnaround), not coverable by more chains.
// R11 ledger: x-MFMA pipeline works ONLY as {loads hoisted to step top,
// accx MFMAs sunk after gates}; R10: bank conflicts off-path, HPAD=144
// known-good (16B-aligned rows).
// NaN ledger: R1/R5/R7 (vector weight loads, plain body) and R6 (K=16 f16)
// all NaN'd; R2/R3/R8/R11 (scalar loads + sniff dispatcher) passed. Do not
// reintroduce those factors without an isolated A/B.

#define T_STEPS 128
#define ISZ 32
#define HSZ 64
#define B_TOT 8192
#define B_TILE 16
#define T_CHUNK 32
#define HPAD 144

typedef short bf16x8 __attribute__((ext_vector_type(8)));
typedef float f32x4 __attribute__((ext_vector_type(4)));

#define LOG2E 1.44269504088896340736f

__device__ __forceinline__ float bf2f(unsigned short s) {
    union { unsigned int u; float f; } v; v.u = ((unsigned int)s) << 16; return v.f;
}
__device__ __forceinline__ unsigned short f2bf(float f) {
    union { float f; unsigned int u; } v; v.f = f;
    unsigned int u = v.u;
    return (unsigned short)((u + 0x7fffu + ((u >> 16) & 1u)) >> 16);  // RNE
}
// tanh = 1 - 2*rcp(1 + exp2(2x*log2e)); +inf -> 1; -inf -> -1. Safe.
// (used only for tanh(cst) — runtime argument, scale not foldable)
__device__ __forceinline__ float tanh_fast(float x) {
    return 1.0f - 2.0f * __builtin_amdgcn_rcpf(1.0f + __builtin_amdgcn_exp2f((2.0f * LOG2E) * x));
}
// prescaled-gate helpers: z already carries the exp2 scale (folded into W).
// sig_pre: z = -LOG2E*x -> sigmoid(x). z->+inf: exp2->inf, rcp->0. Safe.
__device__ __forceinline__ float sig_pre(float z) {
    return __builtin_amdgcn_rcpf(1.0f + __builtin_amdgcn_exp2f(z));
}
// tanh_pre: z = 2*LOG2E*x -> tanh(x). Safe at +-inf as before.
__device__ __forceinline__ float tanh_pre(float z) {
    return 1.0f - 2.0f * __builtin_amdgcn_rcpf(1.0f + __builtin_amdgcn_exp2f(z));
}

template <bool F32>
__device__ __forceinline__ float ldin(const void* p, size_t i) {
    if (F32) return ((const float*)p)[i];
    return bf2f(((const unsigned short*)p)[i]);
}

template <bool F32>
__device__ __forceinline__ void run_body(
    const void* xv, const void* Wihv, const void* Whhv, const void* bihv,
    const void* bhhv, const void* Wfcv, const void* bfcv, void* outv,
    unsigned short (&hbuf)[2][B_TILE][HPAD],
    unsigned short (&xbuf)[T_CHUNK][B_TILE][40],
    float (&hfin)[B_TILE][HSZ + 4])
{
    const int tid  = threadIdx.x;
    const int wid  = tid >> 6;
    const int lane = tid & 63;
    const int q    = lane >> 4;   // A/B frag k-quad; C/D row-quad
    const int tn   = lane & 15;   // A: batch row m; B/C: unit col n
    const int u    = wid * 16 + tn;
    const int b0   = blockIdx.x * B_TILE;

    // B-operand weight frags, loaded once (scalar loads — see NaN ledger).
    // Exp2 scale folded in: i/f/o rows x (-LOG2E), g rows x (+2*LOG2E),
    // applied in fp32 BEFORE the single bf16 rounding (same error profile).
    bf16x8 wf[4][3];
    f32x4 biasC[4];   // bias broadcast into a C-operand vector: no acc-init movs
    #pragma unroll
    for (int g = 0; g < 4; ++g) {
        const float sc = (g == 2) ? (2.0f * LOG2E) : (-LOG2E);
        const int row = g * HSZ + u;
        #pragma unroll
        for (int j = 0; j < 8; ++j) {
            wf[g][0][j] = (short)f2bf(sc * ldin<F32>(Whhv, row * HSZ + q * 8 + j));
            wf[g][1][j] = (short)f2bf(sc * ldin<F32>(Whhv, row * HSZ + 32 + q * 8 + j));
            wf[g][2][j] = (short)f2bf(sc * ldin<F32>(Wihv, row * ISZ + q * 8 + j));
        }
        const float b = sc * (ldin<F32>(bihv, row) + ldin<F32>(bhhv, row));
        #pragma unroll
        for (int e = 0; e < 4; ++e) biasC[g][e] = b;
    }

    // h(0) = 0
    for (int i = tid; i < 2 * B_TILE * HPAD; i += 256) ((unsigned short*)hbuf)[i] = 0;

    float cst[4] = {0.f, 0.f, 0.f, 0.f};
    float hl[4]  = {0.f, 0.f, 0.f, 0.f};
    f32x4 accx[4];

    for (int tc = 0; tc < T_STEPS / T_CHUNK; ++tc) {
        // stage x[b0..+16)[tc*32..+32)[0..32) -> xbuf[t][m][k]; prev chunk's
        // reads finished at the last step's barrier, so no barrier needed here.
        if (F32) {
            const float* xf = (const float*)xv;
            for (int idx = tid; idx < B_TILE * T_CHUNK * 4; idx += 256) {
                const int m  = idx >> 7;
                const int rm = idx & 127;
                const int tl = rm >> 2;
                const int ch = rm & 3;
                const size_t base = ((size_t)(b0 + m) * T_STEPS + (tc * T_CHUNK + tl)) * ISZ + ch * 8;
                const f32x4 v0 = *(const f32x4*)(xf + base);
                const f32x4 v1 = *(const f32x4*)(xf + base + 4);
                bf16x8 w;
                #pragma unroll
                for (int j = 0; j < 4; ++j) {
                    w[j]     = (short)f2bf(v0[j]);
                    w[4 + j] = (short)f2bf(v1[j]);
                }
                *(bf16x8*)&xbuf[tl][m][ch * 8] = w;
            }
        } else {
            const unsigned short* xu = (const unsigned short*)xv;
            for (int idx = tid; idx < B_TILE * T_CHUNK * 4; idx += 256) {
                const int m  = idx >> 7;
                const int rm = idx & 127;
                const int tl = rm >> 2;
                const int ch = rm & 3;
                const uint4 v = *(const uint4*)(xu + ((size_t)(b0 + m) * T_STEPS + (tc * T_CHUNK + tl)) * ISZ + ch * 8);
                *(uint4*)&xbuf[tl][m][ch * 8] = v;
            }
        }
        __syncthreads();

        // chunk prologue: x-contribution of step tl=0 (bias as C-operand).
        {
            const bf16x8 ax = *(const bf16x8*)&xbuf[0][tn][q * 8];
            #pragma unroll
            for (int g = 0; g < 4; ++g)
                accx[g] = __builtin_amdgcn_mfma_f32_16x16x32_bf16(ax, wf[g][2], biasC[g], 0, 0, 0);
        }

        #pragma unroll 2
        for (int tl = 0; tl < T_CHUNK; ++tl) {
            const int t  = tc * T_CHUNK + tl;
            const int rb = t & 1, wb = rb ^ 1;
            // issue ALL step loads together: h A-frags + next step's x frag.
            // ax2's lgkm wait is deferred to its first use (accx MFMAs, last).
            const bf16x8 a0  = *(const bf16x8*)&hbuf[rb][tn][q * 8];       // h k0..31
            const bf16x8 a1  = *(const bf16x8*)&hbuf[rb][tn][32 + q * 8];  // h k32..63
            const bf16x8 ax2 = *(const bf16x8*)&xbuf[(tl + 1) & (T_CHUNK - 1)][tn][q * 8];

            __builtin_amdgcn_s_setprio(1);
            f32x4 acc[4];
            #pragma unroll
            for (int g = 0; g < 4; ++g)
                acc[g] = __builtin_amdgcn_mfma_f32_16x16x32_bf16(a0, wf[g][0], accx[g], 0, 0, 0);
            #pragma unroll
            for (int g = 0; g < 4; ++g)
                acc[g] = __builtin_amdgcn_mfma_f32_16x16x32_bf16(a1, wf[g][1], acc[g], 0, 0, 0);
            __builtin_amdgcn_s_setprio(0);

            // gate trans phase first (issue-dominant burst); exp2 args come
            // straight from the MFMA output (scale pre-folded into W).
            #pragma unroll
            for (int r = 0; r < 4; ++r) {
                const float gi = sig_pre(acc[0][r]);
                const float gf = sig_pre(acc[1][r]);
                const float gg = tanh_pre(acc[2][r]);
                const float go = sig_pre(acc[3][r]);
                cst[r] = gf * cst[r] + gi * gg;
                const float hv = go * tanh_fast(cst[r]);
                hl[r] = hv;
                const int m = q * 4 + r;  // C/D row = batch
                hbuf[wb][m][u] = f2bf(hv);
            }

            // next step's x-contribution LAST: fills the write/barrier window.
            // (tl+1)&31 wraps to stale xbuf[0] on the last step; that accx is
            // discarded (next chunk's prologue recomputes from fresh data),
            // and the read precedes the staging barrier -> no race.
            #pragma unroll
            for (int g = 0; g < 4; ++g)
                accx[g] = __builtin_amdgcn_mfma_f32_16x16x32_bf16(ax2, wf[g][2], biasC[g], 0, 0, 0);

            __syncthreads();
        }
    }

    // epilogue: out[b][j] = h_T(fp32) . Wfc[j,:] + bfc[j]
    #pragma unroll
    for (int r = 0; r < 4; ++r) hfin[q * 4 + r][u] = hl[r];
    __syncthreads();
    if (tid < B_TILE * 8) {
        const int m = tid >> 3, j = tid & 7;
        float s = ldin<F32>(bfcv, j);
        #pragma unroll
        for (int k = 0; k < HSZ; ++k) s += hfin[m][k] * ldin<F32>(Wfcv, j * HSZ + k);
        const size_t o = (size_t)(b0 + m) * 8 + j;
        if (F32) ((float*)outv)[o] = s;
        else     ((unsigned short*)outv)[o] = f2bf(s);
    }
}

__global__ __launch_bounds__(256, 2) void lstm_fused(
    const void* __restrict__ x, const void* __restrict__ Wih,
    const void* __restrict__ Whh, const void* __restrict__ bih,
    const void* __restrict__ bhh, const void* __restrict__ Wfc,
    const void* __restrict__ bfc, void* __restrict__ out)
{
    __shared__ unsigned short hbuf[2][B_TILE][HPAD];
    __shared__ unsigned short xbuf[T_CHUNK][B_TILE][40];
    __shared__ float hfin[B_TILE][HSZ + 4];

    // dtype sniff (guard): fp32 data read as uint16 halves has mantissa-garbage
    // halves decoding to huge-exponent bf16s; real bf16 data never exceeds 2^17.
    const unsigned short* xu = (const unsigned short*)x;
    const int lane = threadIdx.x & 63;
    const unsigned short s0 = xu[lane * 2];
    const unsigned short s1 = xu[lane * 2 + 1];
    const int big = (((s0 >> 7) & 0xFF) >= 0x90) || (((s1 >> 7) & 0xFF) >= 0x90);
    const bool isf32 = __any(big) != 0;

    if (isf32) run_body<true >(x, Wih, Whh, bih, bhh, Wfc, bfc, out, hbuf, xbuf, hfin);
    else       run_body<false>(x, Wih, Whh, bih, bhh, Wfc, bfc, out, hbuf, xbuf, hfin);
}

extern "C" void kernel_launch(void* const* d_in, const int* in_sizes, int n_in,
                              void* d_out, int out_size, void* d_ws, size_t ws_size,
                              hipStream_t stream) {
    lstm_fused<<<dim3(B_TOT / B_TILE), dim3(256), 0, stream>>>(
        d_in[0], d_in[1], d_in[2], d_in[3], d_in[4], d_in[5], d_in[6], d_out);
}

// Round 7
// 263.846 us; speedup vs baseline: 1.2168x; 1.0170x over previous
//
#include <hip/hip_runtime.h>
#include <stdint.h>

// LSTM fused: B=8192, T=128, I=32, H=64, OUT=8. fp32 internal state, bf16 MFMA.
// R15 = R14 (best, 130.4us) + two critical-path edits, structure frozen:
//   (1) accx MFMAs moved END -> TOP of step, consuming the x-frag read in the
//       PREVIOUS iteration (register-carried axc). Post-barrier order: issue
//       ds_reads (a0,a1,ax_next) -> 4 accx MFMAs (reg operands, no wait;
//       covers a0's ~120cy lgkm) -> h-MFMAs -> gates -> write -> barrier.
//       Step tail is now empty -> earlier barrier arrival.
//   (2) cst kept in 2*log2e domain (cstS): ggS = fma(rcp,-4L,2L) (same op
//       count as 1-2r), cstS = gf*cstS + gi*ggS, tanh(c) = 1-2*rcp(1+exp2(
//       cstS)) -> deletes the head mul of the output-tanh serial tail.
// Issue model (R14 counters): trans floor 640 cyc/SIMD/step (80 instr x 8cy),
// non-trans VALU ~610, MFMA ~390, exposed stall ~800-1000 (ds_read + barrier).
// Structure ledger (do not revisit): 2 waves/SIMD optimum — R12 (4 chains,
// garbage rows) 154us, R13 (1 wave/SIMD 2-tile ILP) 185us, R9 (8-wave
// barrier) 184us. R11: x-pipeline needs {loads hoisted, dependent MFMAs
// placed off the lgkm wait}; R10: bank conflicts off-path, HPAD=144
// known-good. R14: weight-prescale (exp2 scale folded into W/bias) + setprio
// both net-positive.
// NaN ledger: R1/R5/R7 (vector weight loads, plain body) and R6 (K=16 f16)
// all NaN'd; R2/R3/R8/R11/R14 (scalar loads + sniff dispatcher) passed. Do
// not reintroduce those factors without an isolated A/B.

#define T_STEPS 128
#define ISZ 32
#define HSZ 64
#define B_TOT 8192
#define B_TILE 16
#define T_CHUNK 32
#define HPAD 144

typedef short bf16x8 __attribute__((ext_vector_type(8)));
typedef float f32x4 __attribute__((ext_vector_type(4)));

#define LOG2E 1.44269504088896340736f

__device__ __forceinline__ float bf2f(unsigned short s) {
    union { unsigned int u; float f; } v; v.u = ((unsigned int)s) << 16; return v.f;
}
__device__ __forceinline__ unsigned short f2bf(float f) {
    union { float f; unsigned int u; } v; v.f = f;
    unsigned int u = v.u;
    return (unsigned short)((u + 0x7fffu + ((u >> 16) & 1u)) >> 16);  // RNE
}
// prescaled-gate helpers: z already carries the exp2 scale (folded into W).
// sig_pre: z = -LOG2E*x -> sigmoid(x). z->+inf: exp2->inf, rcp->0. Safe.
__device__ __forceinline__ float sig_pre(float z) {
    return __builtin_amdgcn_rcpf(1.0f + __builtin_amdgcn_exp2f(z));
}

template <bool F32>
__device__ __forceinline__ float ldin(const void* p, size_t i) {
    if (F32) return ((const float*)p)[i];
    return bf2f(((const unsigned short*)p)[i]);
}

template <bool F32>
__device__ __forceinline__ void run_body(
    const void* xv, const void* Wihv, const void* Whhv, const void* bihv,
    const void* bhhv, const void* Wfcv, const void* bfcv, void* outv,
    unsigned short (&hbuf)[2][B_TILE][HPAD],
    unsigned short (&xbuf)[T_CHUNK][B_TILE][40],
    float (&hfin)[B_TILE][HSZ + 4])
{
    const int tid  = threadIdx.x;
    const int wid  = tid >> 6;
    const int lane = tid & 63;
    const int q    = lane >> 4;   // A/B frag k-quad; C/D row-quad
    const int tn   = lane & 15;   // A: batch row m; B/C: unit col n
    const int u    = wid * 16 + tn;
    const int b0   = blockIdx.x * B_TILE;

    // B-operand weight frags, loaded once (scalar loads — see NaN ledger).
    // Exp2 scale folded in: i/f/o rows x (-LOG2E), g rows x (+2*LOG2E),
    // applied in fp32 BEFORE the single bf16 rounding (same error profile).
    bf16x8 wf[4][3];
    f32x4 biasC[4];   // bias broadcast into a C-operand vector: no acc-init movs
    #pragma unroll
    for (int g = 0; g < 4; ++g) {
        const float sc = (g == 2) ? (2.0f * LOG2E) : (-LOG2E);
        const int row = g * HSZ + u;
        #pragma unroll
        for (int j = 0; j < 8; ++j) {
            wf[g][0][j] = (short)f2bf(sc * ldin<F32>(Whhv, row * HSZ + q * 8 + j));
            wf[g][1][j] = (short)f2bf(sc * ldin<F32>(Whhv, row * HSZ + 32 + q * 8 + j));
            wf[g][2][j] = (short)f2bf(sc * ldin<F32>(Wihv, row * ISZ + q * 8 + j));
        }
        const float b = sc * (ldin<F32>(bihv, row) + ldin<F32>(bhhv, row));
        #pragma unroll
        for (int e = 0; e < 4; ++e) biasC[g][e] = b;
    }

    // h(0) = 0
    for (int i = tid; i < 2 * B_TILE * HPAD; i += 256) ((unsigned short*)hbuf)[i] = 0;

    // c-state kept in the 2*log2e domain (cstS = 2*LOG2E * c).
    float cstS[4] = {0.f, 0.f, 0.f, 0.f};
    float hl[4]   = {0.f, 0.f, 0.f, 0.f};

    for (int tc = 0; tc < T_STEPS / T_CHUNK; ++tc) {
        // stage x[b0..+16)[tc*32..+32)[0..32) -> xbuf[t][m][k]; prev chunk's
        // reads finished at the last step's barrier, so no barrier needed here.
        if (F32) {
            const float* xf = (const float*)xv;
            for (int idx = tid; idx < B_TILE * T_CHUNK * 4; idx += 256) {
                const int m  = idx >> 7;
                const int rm = idx & 127;
                const int tl = rm >> 2;
                const int ch = rm & 3;
                const size_t base = ((size_t)(b0 + m) * T_STEPS + (tc * T_CHUNK + tl)) * ISZ + ch * 8;
                const f32x4 v0 = *(const f32x4*)(xf + base);
                const f32x4 v1 = *(const f32x4*)(xf + base + 4);
                bf16x8 w;
                #pragma unroll
                for (int j = 0; j < 4; ++j) {
                    w[j]     = (short)f2bf(v0[j]);
                    w[4 + j] = (short)f2bf(v1[j]);
                }
                *(bf16x8*)&xbuf[tl][m][ch * 8] = w;
            }
        } else {
            const unsigned short* xu = (const unsigned short*)xv;
            for (int idx = tid; idx < B_TILE * T_CHUNK * 4; idx += 256) {
                const int m  = idx >> 7;
                const int rm = idx & 127;
                const int tl = rm >> 2;
                const int ch = rm & 3;
                const uint4 v = *(const uint4*)(xu + ((size_t)(b0 + m) * T_STEPS + (tc * T_CHUNK + tl)) * ISZ + ch * 8);
                *(uint4*)&xbuf[tl][m][ch * 8] = v;
            }
        }
        __syncthreads();

        // chunk prologue: register-carry the x-frag of step tl=0.
        bf16x8 axc = *(const bf16x8*)&xbuf[0][tn][q * 8];

        #pragma unroll 2
        for (int tl = 0; tl < T_CHUNK; ++tl) {
            const int t  = tc * T_CHUNK + tl;
            const int rb = t & 1, wb = rb ^ 1;
            // issue ALL step loads together: h A-frags + next step's x frag.
            // ax_next's lgkm wait is deferred to next iteration's accx MFMAs.
            const bf16x8 a0  = *(const bf16x8*)&hbuf[rb][tn][q * 8];       // h k0..31
            const bf16x8 a1  = *(const bf16x8*)&hbuf[rb][tn][32 + q * 8];  // h k32..63
            const bf16x8 axn = *(const bf16x8*)&xbuf[(tl + 1) & (T_CHUNK - 1)][tn][q * 8];

            __builtin_amdgcn_s_setprio(1);
            // x-contribution FIRST, from register-carried axc (no lgkm wait):
            // its issue+pipe latency covers part of a0/a1's ds_read latency.
            f32x4 acc[4];
            #pragma unroll
            for (int g = 0; g < 4; ++g)
                acc[g] = __builtin_amdgcn_mfma_f32_16x16x32_bf16(axc, wf[g][2], biasC[g], 0, 0, 0);
            #pragma unroll
            for (int g = 0; g < 4; ++g)
                acc[g] = __builtin_amdgcn_mfma_f32_16x16x32_bf16(a0, wf[g][0], acc[g], 0, 0, 0);
            #pragma unroll
            for (int g = 0; g < 4; ++g)
                acc[g] = __builtin_amdgcn_mfma_f32_16x16x32_bf16(a1, wf[g][1], acc[g], 0, 0, 0);
            __builtin_amdgcn_s_setprio(0);

            // gate trans phase; exp2 args come straight from the MFMA output
            // (scale pre-folded into W). cstS in 2*log2e domain: no head mul
            // on the output-tanh chain.
            #pragma unroll
            for (int r = 0; r < 4; ++r) {
                const float gi  = sig_pre(acc[0][r]);
                const float gf  = sig_pre(acc[1][r]);
                const float rg  = __builtin_amdgcn_rcpf(1.0f + __builtin_amdgcn_exp2f(acc[2][r]));
                const float ggS = __builtin_fmaf(rg, -4.0f * LOG2E, 2.0f * LOG2E);  // 2L*tanh
                const float go  = sig_pre(acc[3][r]);
                cstS[r] = gf * cstS[r] + gi * ggS;
                const float th = 1.0f - 2.0f * __builtin_amdgcn_rcpf(1.0f + __builtin_amdgcn_exp2f(cstS[r]));
                const float hv = go * th;
                hl[r] = hv;
                const int m = q * 4 + r;  // C/D row = batch
                hbuf[wb][m][u] = f2bf(hv);
            }

            axc = axn;  // carry next step's x frag (register rename)
            __syncthreads();
        }
    }

    // epilogue: out[b][j] = h_T(fp32) . Wfc[j,:] + bfc[j]
    #pragma unroll
    for (int r = 0; r < 4; ++r) hfin[q * 4 + r][u] = hl[r];
    __syncthreads();
    if (tid < B_TILE * 8) {
        const int m = tid >> 3, j = tid & 7;
        float s = ldin<F32>(bfcv, j);
        #pragma unroll
        for (int k = 0; k < HSZ; ++k) s += hfin[m][k] * ldin<F32>(Wfcv, j * HSZ + k);
        const size_t o = (size_t)(b0 + m) * 8 + j;
        if (F32) ((float*)outv)[o] = s;
        else     ((unsigned short*)outv)[o] = f2bf(s);
    }
}

__global__ __launch_bounds__(256, 2) void lstm_fused(
    const void* __restrict__ x, const void* __restrict__ Wih,
    const void* __restrict__ Whh, const void* __restrict__ bih,
    const void* __restrict__ bhh, const void* __restrict__ Wfc,
    const void* __restrict__ bfc, void* __restrict__ out)
{
    __shared__ unsigned short hbuf[2][B_TILE][HPAD];
    __shared__ unsigned short xbuf[T_CHUNK][B_TILE][40];
    __shared__ float hfin[B_TILE][HSZ + 4];

    // dtype sniff (guard): fp32 data read as uint16 halves has mantissa-garbage
    // halves decoding to huge-exponent bf16s; real bf16 data never exceeds 2^17.
    const unsigned short* xu = (const unsigned short*)x;
    const int lane = threadIdx.x & 63;
    const unsigned short s0 = xu[lane * 2];
    const unsigned short s1 = xu[lane * 2 + 1];
    const int big = (((s0 >> 7) & 0xFF) >= 0x90) || (((s1 >> 7) & 0xFF) >= 0x90);
    const bool isf32 = __any(big) != 0;

    if (isf32) run_body<true >(x, Wih, Whh, bih, bhh, Wfc, bfc, out, hbuf, xbuf, hfin);
    else       run_body<false>(x, Wih, Whh, bih, bhh, Wfc, bfc, out, hbuf, xbuf, hfin);
}

extern "C" void kernel_launch(void* const* d_in, const int* in_sizes, int n_in,
                              void* d_out, int out_size, void* d_ws, size_t ws_size,
                              hipStream_t stream) {
    lstm_fused<<<dim3(B_TOT / B_TILE), dim3(256), 0, stream>>>(
        d_in[0], d_in[1], d_in[2], d_in[3], d_in[4], d_in[5], d_in[6], d_out);
}